// Round 1
// baseline (172.773 us; speedup 1.0000x reference)
//
#include <hip/hip_runtime.h>

#define B_ 32
#define T_ 2048
#define C_ 64
#define NP_ 2060          // unique p positions per batch: t + 2k, t<2048, k<7
#define MSTRIDE 144       // floats per 12x12 matrix in global ws
#define LSTRIDE 148       // padded LDS stride (592 B, 16B-aligned, kills bank conflicts)

// ------------------------------------------------------------------
// K1: M[b][p][h][w] = sum_c (xp[p+2,c]-xp[p,c]) * (A[c][h][w]-A[c][w][h])
//     xp[j] = x[clamp(j-7, 0, 2047)]  (edge padding, pad=7)
// ------------------------------------------------------------------
__global__ __launch_bounds__(256) void k1_build(const float* __restrict__ x,
                                                const float* __restrict__ A,
                                                float* __restrict__ M) {
  __shared__ float ask[64][144];   // skew-symmetrized A
  __shared__ float dx[64][65];     // +1 pad: conflict-free column reads
  const int b = blockIdx.y;
  const int p0 = blockIdx.x * 64;
  const int tid = threadIdx.x;

  for (int i = tid; i < 64 * 144; i += 256) {
    int c = i / 144, e = i - c * 144;
    int h = e / 12, w = e - h * 12;
    ask[c][e] = A[c * 144 + e] - A[c * 144 + w * 12 + h];
  }
  for (int i = tid; i < 64 * 64; i += 256) {
    int pl = i >> 6, c = i & 63;
    int p = p0 + pl;
    float v = 0.f;
    if (p < NP_) {
      int i1 = min(max(p - 7, 0), T_ - 1);
      int i2 = min(max(p - 5, 0), T_ - 1);
      const float* xb = x + (size_t)b * T_ * C_;
      v = xb[(size_t)i2 * C_ + c] - xb[(size_t)i1 * C_ + c];
    }
    dx[pl][c] = v;
  }
  __syncthreads();

  const int eg = tid & 3;          // 4 col-groups of 36
  const int nl = tid >> 2;         // 64 p's per block
  const int p = p0 + nl;
  const int e0 = eg * 36;
  float acc[36];
#pragma unroll
  for (int j = 0; j < 36; ++j) acc[j] = 0.f;

  for (int c = 0; c < 64; ++c) {
    float d = dx[nl][c];
    const float4* ar = (const float4*)&ask[c][e0];
#pragma unroll
    for (int q = 0; q < 9; ++q) {
      float4 v = ar[q];
      acc[q * 4 + 0] += d * v.x;
      acc[q * 4 + 1] += d * v.y;
      acc[q * 4 + 2] += d * v.z;
      acc[q * 4 + 3] += d * v.w;
    }
  }
  if (p < NP_) {
    float* mp = M + ((size_t)b * NP_ + p) * MSTRIDE + e0;
#pragma unroll
    for (int q = 0; q < 9; ++q) {
      *(float4*)(mp + q * 4) =
          make_float4(acc[q * 4 + 0], acc[q * 4 + 1], acc[q * 4 + 2], acc[q * 4 + 3]);
    }
  }
}

// ------------------------------------------------------------------
// Shared matmul helper: c[3][12] = a_rows(3x12, regs) * Blds(12x12, LDS)
// All 4 lanes of a group read the same LDS addresses (broadcast, free).
// ------------------------------------------------------------------
__device__ __forceinline__ void matmul_rows(const float a[3][12], const float* lb,
                                            float c[3][12]) {
#pragma unroll
  for (int i = 0; i < 3; ++i)
#pragma unroll
    for (int j = 0; j < 12; ++j) c[i][j] = 0.f;
#pragma unroll
  for (int k = 0; k < 12; ++k) {
    float4 b0 = *(const float4*)(lb + k * 12 + 0);
    float4 b1 = *(const float4*)(lb + k * 12 + 4);
    float4 b2 = *(const float4*)(lb + k * 12 + 8);
#pragma unroll
    for (int i = 0; i < 3; ++i) {
      const float a_ = a[i][k];
      c[i][0] += a_ * b0.x;  c[i][1] += a_ * b0.y;  c[i][2]  += a_ * b0.z;  c[i][3]  += a_ * b0.w;
      c[i][4] += a_ * b1.x;  c[i][5] += a_ * b1.y;  c[i][6]  += a_ * b1.z;  c[i][7]  += a_ * b1.w;
      c[i][8] += a_ * b2.x;  c[i][9] += a_ * b2.y;  c[i][10] += a_ * b2.z;  c[i][11] += a_ * b2.w;
    }
  }
}

// ------------------------------------------------------------------
// K2: in-place E = expm(M).  Fixed scaling s=7 (scale 1/128), Taylor order 8,
// 7 squarings. 4 lanes per matrix (3 rows each), 16 matrices/wave, 64/block.
// Uniform control flow -> __syncthreads is safe and cheap insurance.
// ------------------------------------------------------------------
__global__ __launch_bounds__(256) void k2_expm(float* __restrict__ M) {
  __shared__ float buf[64][LSTRIDE];
  const int tid = threadIdx.x;
  const int lane = tid & 63;
  const int wave = tid >> 6;
  const int g = lane >> 2, r = lane & 3;
  const int mloc = wave * 16 + g;
  const size_t mid = (size_t)blockIdx.x * 64 + mloc;
  float* gp = M + mid * MSTRIDE;
  float* lb = &buf[mloc][0];

  float t[3][12], s[3][12];
  const float sc = 1.0f / 128.0f;   // 2^-7

  // load my 3 rows, scale
#pragma unroll
  for (int i = 0; i < 3; ++i) {
    const int row = 3 * r + i;
#pragma unroll
    for (int q = 0; q < 3; ++q) {
      float4 v = *(const float4*)(gp + row * 12 + q * 4);
      t[i][q * 4 + 0] = v.x * sc;
      t[i][q * 4 + 1] = v.y * sc;
      t[i][q * 4 + 2] = v.z * sc;
      t[i][q * 4 + 3] = v.w * sc;
    }
  }
  // write M0 to LDS
#pragma unroll
  for (int i = 0; i < 3; ++i) {
    const int row = 3 * r + i;
    *(float4*)(lb + row * 12 + 0) = make_float4(t[i][0], t[i][1], t[i][2],  t[i][3]);
    *(float4*)(lb + row * 12 + 4) = make_float4(t[i][4], t[i][5], t[i][6],  t[i][7]);
    *(float4*)(lb + row * 12 + 8) = make_float4(t[i][8], t[i][9], t[i][10], t[i][11]);
  }
  __syncthreads();

  // S = I + T1
#pragma unroll
  for (int i = 0; i < 3; ++i)
#pragma unroll
    for (int j = 0; j < 12; ++j)
      s[i][j] = t[i][j] + ((3 * r + i == j) ? 1.0f : 0.0f);

  // Taylor terms T2..T8: T_j = (T_{j-1} * M0) / j ; S += T_j
  for (int jt = 2; jt <= 8; ++jt) {
    float c[3][12];
    matmul_rows(t, lb, c);
    const float inv = 1.0f / (float)jt;
#pragma unroll
    for (int i = 0; i < 3; ++i)
#pragma unroll
      for (int j = 0; j < 12; ++j) {
        t[i][j] = c[i][j] * inv;
        s[i][j] += t[i][j];
      }
  }

  // 7 squarings: S <- S*S (S staged in LDS, own rows from regs)
  for (int sq = 0; sq < 7; ++sq) {
#pragma unroll
    for (int i = 0; i < 3; ++i) {
      const int row = 3 * r + i;
      *(float4*)(lb + row * 12 + 0) = make_float4(s[i][0], s[i][1], s[i][2],  s[i][3]);
      *(float4*)(lb + row * 12 + 4) = make_float4(s[i][4], s[i][5], s[i][6],  s[i][7]);
      *(float4*)(lb + row * 12 + 8) = make_float4(s[i][8], s[i][9], s[i][10], s[i][11]);
    }
    __syncthreads();
    float c[3][12];
    matmul_rows(s, lb, c);
    __syncthreads();
#pragma unroll
    for (int i = 0; i < 3; ++i)
#pragma unroll
      for (int j = 0; j < 12; ++j) s[i][j] = c[i][j];
  }

  // write E back in-place
#pragma unroll
  for (int i = 0; i < 3; ++i) {
    const int row = 3 * r + i;
    *(float4*)(gp + row * 12 + 0) = make_float4(s[i][0], s[i][1], s[i][2],  s[i][3]);
    *(float4*)(gp + row * 12 + 4) = make_float4(s[i][4], s[i][5], s[i][6],  s[i][7]);
    *(float4*)(gp + row * 12 + 8) = make_float4(s[i][8], s[i][9], s[i][10], s[i][11]);
  }
}

// ------------------------------------------------------------------
// K3: per window t: Z = E(t) * E(t+2) * ... * E(t+12); out = [Z(144), xp[t](64)]
// 64 windows/block (fixed b); stage the 76 needed E's in LDS (shared by waves).
// ------------------------------------------------------------------
__global__ __launch_bounds__(256) void k3_chain(const float* __restrict__ E,
                                                const float* __restrict__ x,
                                                float* __restrict__ out) {
  __shared__ float eb[76][LSTRIDE];
  const int b = blockIdx.y;
  const int t0 = blockIdx.x * 64;
  const float* src = E + ((size_t)b * NP_ + t0) * MSTRIDE;
  for (int i = threadIdx.x; i < 76 * 36; i += 256) {
    int m = i / 36, q = i - m * 36;
    *(float4*)(&eb[m][q * 4]) = *(const float4*)(src + (size_t)m * MSTRIDE + q * 4);
  }
  __syncthreads();

  const int lane = threadIdx.x & 63;
  const int wave = threadIdx.x >> 6;
  const int g = lane >> 2, r = lane & 3;
  const int tl = wave * 16 + g;     // 0..63
  const int t = t0 + tl;

  float z[3][12];
#pragma unroll
  for (int i = 0; i < 3; ++i) {
    const int row = 3 * r + i;
    float4 v0 = *(const float4*)(&eb[tl][row * 12 + 0]);
    float4 v1 = *(const float4*)(&eb[tl][row * 12 + 4]);
    float4 v2 = *(const float4*)(&eb[tl][row * 12 + 8]);
    z[i][0] = v0.x; z[i][1] = v0.y; z[i][2]  = v0.z; z[i][3]  = v0.w;
    z[i][4] = v1.x; z[i][5] = v1.y; z[i][6]  = v1.z; z[i][7]  = v1.w;
    z[i][8] = v2.x; z[i][9] = v2.y; z[i][10] = v2.z; z[i][11] = v2.w;
  }
  for (int j = 1; j <= 6; ++j) {
    const float* ep = &eb[tl + 2 * j][0];
    float c[3][12];
    matmul_rows(z, ep, c);
#pragma unroll
    for (int i = 0; i < 3; ++i)
#pragma unroll
      for (int jj = 0; jj < 12; ++jj) z[i][jj] = c[i][jj];
  }

  const size_t obase = ((size_t)b * T_ + t) * 208;
#pragma unroll
  for (int i = 0; i < 3; ++i) {
    const int row = 3 * r + i;
    *(float4*)(out + obase + row * 12 + 0) = make_float4(z[i][0], z[i][1], z[i][2],  z[i][3]);
    *(float4*)(out + obase + row * 12 + 4) = make_float4(z[i][4], z[i][5], z[i][6],  z[i][7]);
    *(float4*)(out + obase + row * 12 + 8) = make_float4(z[i][8], z[i][9], z[i][10], z[i][11]);
  }
  const int xi = min(max(t - 7, 0), T_ - 1);
  const float* xr = x + ((size_t)b * T_ + xi) * C_ + 16 * r;
#pragma unroll
  for (int q = 0; q < 4; ++q) {
    *(float4*)(out + obase + 144 + 16 * r + q * 4) = *(const float4*)(xr + q * 4);
  }
}

// ------------------------------------------------------------------
extern "C" void kernel_launch(void* const* d_in, const int* in_sizes, int n_in,
                              void* d_out, int out_size, void* d_ws, size_t ws_size,
                              hipStream_t stream) {
  (void)in_sizes; (void)n_in; (void)out_size;
  const float* x = (const float*)d_in[0];
  const float* A = (const float*)d_in[1];
  float* out = (float*)d_out;
  float* M = (float*)d_ws;

  const size_t need = (size_t)B_ * NP_ * MSTRIDE * sizeof(float);  // ~38 MB
  if (ws_size < need) return;  // fail loudly via validation rather than corrupt

  k1_build<<<dim3(33, B_), 256, 0, stream>>>(x, A, M);
  k2_expm<<<dim3((B_ * NP_) / 64), 256, 0, stream>>>(M);           // 1030 blocks
  k3_chain<<<dim3(T_ / 64, B_), 256, 0, stream>>>(M, x, out);
}

// Round 2
// 149.813 us; speedup vs baseline: 1.1533x; 1.1533x over previous
//
#include <hip/hip_runtime.h>

#define B_ 32
#define T_ 2048
#define C_ 64
#define NP_ 2060          // unique p positions per batch: t + 2k, t<2048, k<7
#define MSTRIDE 144       // floats per 12x12 matrix in global ws
#define LSTRIDE 148       // padded LDS stride (592 B = 37*16B, 16B-aligned)

// ------------------------------------------------------------------
// Quad-lane DPP broadcast: all 4 lanes of a quad get lane Q's value.
// Pure VALU (v_mov_b32_dpp quad_perm) — no LDS, no barriers.
// ------------------------------------------------------------------
template <int Q>
__device__ __forceinline__ float qb(float v) {
  return __int_as_float(
      __builtin_amdgcn_mov_dpp(__float_as_int(v), Q * 0x55, 0xf, 0xf, true));
}

// C(3x12, own rows) = A(3x12, own rows) * B(12x12, quad-distributed rows)
// Lane r of the quad owns rows 3r..3r+2 of A, B, C. All indices static.
__device__ __forceinline__ void qmm(const float a[3][12], const float b[3][12],
                                    float c[3][12]) {
#pragma unroll
  for (int i = 0; i < 3; ++i)
#pragma unroll
    for (int j = 0; j < 12; ++j) c[i][j] = 0.f;
#define QMM_K(OWNER, E)                                                  \
  {                                                                      \
    float bk[12];                                                        \
    _Pragma("unroll")                                                    \
    for (int j = 0; j < 12; ++j) bk[j] = qb<OWNER>(b[E][j]);             \
    _Pragma("unroll")                                                    \
    for (int i = 0; i < 3; ++i) {                                        \
      const float av = a[i][3 * OWNER + E];                              \
      _Pragma("unroll")                                                  \
      for (int j = 0; j < 12; ++j) c[i][j] = fmaf(av, bk[j], c[i][j]);   \
    }                                                                    \
  }
  QMM_K(0, 0) QMM_K(0, 1) QMM_K(0, 2)
  QMM_K(1, 0) QMM_K(1, 1) QMM_K(1, 2)
  QMM_K(2, 0) QMM_K(2, 1) QMM_K(2, 2)
  QMM_K(3, 0) QMM_K(3, 1) QMM_K(3, 2)
#undef QMM_K
}

// ------------------------------------------------------------------
// K1: M[b][p][h][w] = sum_c (xp[p+2,c]-xp[p,c]) * (A[c][h][w]-A[c][w][h])
//     xp[j] = x[clamp(j-7, 0, 2047)]  (edge padding, pad=7)
// ------------------------------------------------------------------
__global__ __launch_bounds__(256) void k1_build(const float* __restrict__ x,
                                                const float* __restrict__ A,
                                                float* __restrict__ M) {
  __shared__ float ask[64][144];   // skew-symmetrized A
  __shared__ float dx[64][65];     // +1 pad: conflict-free column reads
  const int b = blockIdx.y;
  const int p0 = blockIdx.x * 64;
  const int tid = threadIdx.x;

  for (int i = tid; i < 64 * 144; i += 256) {
    int c = i / 144, e = i - c * 144;
    int h = e / 12, w = e - h * 12;
    ask[c][e] = A[c * 144 + e] - A[c * 144 + w * 12 + h];
  }
  for (int i = tid; i < 64 * 64; i += 256) {
    int pl = i >> 6, c = i & 63;
    int p = p0 + pl;
    float v = 0.f;
    if (p < NP_) {
      int i1 = min(max(p - 7, 0), T_ - 1);
      int i2 = min(max(p - 5, 0), T_ - 1);
      const float* xb = x + (size_t)b * T_ * C_;
      v = xb[(size_t)i2 * C_ + c] - xb[(size_t)i1 * C_ + c];
    }
    dx[pl][c] = v;
  }
  __syncthreads();

  const int eg = tid & 3;          // 4 col-groups of 36
  const int nl = tid >> 2;         // 64 p's per block
  const int p = p0 + nl;
  const int e0 = eg * 36;
  float acc[36];
#pragma unroll
  for (int j = 0; j < 36; ++j) acc[j] = 0.f;

  for (int c = 0; c < 64; ++c) {
    float d = dx[nl][c];
    const float4* ar = (const float4*)&ask[c][e0];
#pragma unroll
    for (int q = 0; q < 9; ++q) {
      float4 v = ar[q];
      acc[q * 4 + 0] += d * v.x;
      acc[q * 4 + 1] += d * v.y;
      acc[q * 4 + 2] += d * v.z;
      acc[q * 4 + 3] += d * v.w;
    }
  }
  if (p < NP_) {
    float* mp = M + ((size_t)b * NP_ + p) * MSTRIDE + e0;
#pragma unroll
    for (int q = 0; q < 9; ++q) {
      *(float4*)(mp + q * 4) =
          make_float4(acc[q * 4 + 0], acc[q * 4 + 1], acc[q * 4 + 2], acc[q * 4 + 3]);
    }
  }
}

// ------------------------------------------------------------------
// K2: in-place E = expm(M). Horner order-6 Taylor (5 matmuls) with s=6
// scaling (scale 1/64) + 6 squarings. One quad (4 lanes) per matrix,
// 3 rows/lane, everything in registers, DPP broadcasts for the B operand.
// No LDS, no barriers.
// ------------------------------------------------------------------
__global__ __launch_bounds__(256) void k2_expm(float* __restrict__ M) {
  const int gq = (blockIdx.x * 256 + threadIdx.x) >> 2;  // global matrix id
  const int r = threadIdx.x & 3;
  float* gp = M + (size_t)gq * MSTRIDE + 36 * r;  // my 3 rows, contiguous

  const float sc = 1.0f / 64.0f;  // 2^-6
  float m0[3][12], p[3][12], c[3][12];
#pragma unroll
  for (int i = 0; i < 3; ++i)
#pragma unroll
    for (int q4 = 0; q4 < 3; ++q4) {
      float4 v = *(const float4*)(gp + i * 12 + q4 * 4);
      m0[i][q4 * 4 + 0] = v.x * sc;
      m0[i][q4 * 4 + 1] = v.y * sc;
      m0[i][q4 * 4 + 2] = v.z * sc;
      m0[i][q4 * 4 + 3] = v.w * sc;
    }

  // Horner: p = I + m0/6; then p = I + (m0*p)/j for j = 5..1
#pragma unroll
  for (int i = 0; i < 3; ++i)
#pragma unroll
    for (int j = 0; j < 12; ++j)
      p[i][j] = m0[i][j] * (1.0f / 6.0f) + ((j == 3 * r + i) ? 1.0f : 0.0f);

#pragma unroll
  for (int jj = 5; jj >= 1; --jj) {
    qmm(m0, p, c);
    const float inv = 1.0f / (float)jj;
#pragma unroll
    for (int i = 0; i < 3; ++i)
#pragma unroll
      for (int j = 0; j < 12; ++j)
        p[i][j] = c[i][j] * inv + ((j == 3 * r + i) ? 1.0f : 0.0f);
  }

  // 6 squarings (alternating buffers, ends in p)
  qmm(p, p, c);
  qmm(c, c, p);
  qmm(p, p, c);
  qmm(c, c, p);
  qmm(p, p, c);
  qmm(c, c, p);

#pragma unroll
  for (int i = 0; i < 3; ++i)
#pragma unroll
    for (int q4 = 0; q4 < 3; ++q4)
      *(float4*)(gp + i * 12 + q4 * 4) =
          make_float4(p[i][q4 * 4 + 0], p[i][q4 * 4 + 1],
                      p[i][q4 * 4 + 2], p[i][q4 * 4 + 3]);
}

// ------------------------------------------------------------------
// K3: per window t: Z = E(t) * E(t+2) * ... * E(t+12); out = [Z(144), xp[t](64)]
// 64 windows/block (fixed b); stage the 76 needed E's in LDS once, then each
// quad pulls its B rows LDS->regs (9 ds_read_b128) and runs the DPP matmul.
// ------------------------------------------------------------------
__global__ __launch_bounds__(256) void k3_chain(const float* __restrict__ E,
                                                const float* __restrict__ x,
                                                float* __restrict__ out) {
  __shared__ float eb[76][LSTRIDE];
  const int b = blockIdx.y;
  const int t0 = blockIdx.x * 64;
  const float* src = E + ((size_t)b * NP_ + t0) * MSTRIDE;
  for (int i = threadIdx.x; i < 76 * 36; i += 256) {
    int m = i / 36, q = i - m * 36;
    *(float4*)(&eb[m][q * 4]) = *(const float4*)(src + (size_t)m * MSTRIDE + q * 4);
  }
  __syncthreads();

  const int r = threadIdx.x & 3;
  const int tl = threadIdx.x >> 2;  // 0..63, window within block
  const int t = t0 + tl;

  float z[3][12], c[3][12];
#pragma unroll
  for (int i = 0; i < 3; ++i) {
    const float* zp = &eb[tl][(3 * r + i) * 12];
    float4 v0 = *(const float4*)(zp + 0);
    float4 v1 = *(const float4*)(zp + 4);
    float4 v2 = *(const float4*)(zp + 8);
    z[i][0] = v0.x; z[i][1] = v0.y; z[i][2]  = v0.z; z[i][3]  = v0.w;
    z[i][4] = v1.x; z[i][5] = v1.y; z[i][6]  = v1.z; z[i][7]  = v1.w;
    z[i][8] = v2.x; z[i][9] = v2.y; z[i][10] = v2.z; z[i][11] = v2.w;
  }

#define CHAIN_STEP(SRC, DST, J)                                          \
  {                                                                      \
    float bb[3][12];                                                     \
    _Pragma("unroll")                                                    \
    for (int i = 0; i < 3; ++i) {                                        \
      const float* ep = &eb[tl + 2 * (J)][(3 * r + i) * 12];             \
      float4 v0 = *(const float4*)(ep + 0);                              \
      float4 v1 = *(const float4*)(ep + 4);                              \
      float4 v2 = *(const float4*)(ep + 8);                              \
      bb[i][0] = v0.x; bb[i][1] = v0.y; bb[i][2]  = v0.z; bb[i][3]  = v0.w; \
      bb[i][4] = v1.x; bb[i][5] = v1.y; bb[i][6]  = v1.z; bb[i][7]  = v1.w; \
      bb[i][8] = v2.x; bb[i][9] = v2.y; bb[i][10] = v2.z; bb[i][11] = v2.w; \
    }                                                                    \
    qmm(SRC, bb, DST);                                                   \
  }
  CHAIN_STEP(z, c, 1)
  CHAIN_STEP(c, z, 2)
  CHAIN_STEP(z, c, 3)
  CHAIN_STEP(c, z, 4)
  CHAIN_STEP(z, c, 5)
  CHAIN_STEP(c, z, 6)
#undef CHAIN_STEP

  const size_t obase = ((size_t)b * T_ + t) * 208;
#pragma unroll
  for (int i = 0; i < 3; ++i) {
    const int row = 3 * r + i;
    *(float4*)(out + obase + row * 12 + 0) = make_float4(z[i][0], z[i][1], z[i][2],  z[i][3]);
    *(float4*)(out + obase + row * 12 + 4) = make_float4(z[i][4], z[i][5], z[i][6],  z[i][7]);
    *(float4*)(out + obase + row * 12 + 8) = make_float4(z[i][8], z[i][9], z[i][10], z[i][11]);
  }
  const int xi = min(max(t - 7, 0), T_ - 1);
  const float* xr = x + ((size_t)b * T_ + xi) * C_ + 16 * r;
#pragma unroll
  for (int q = 0; q < 4; ++q) {
    *(float4*)(out + obase + 144 + 16 * r + q * 4) = *(const float4*)(xr + q * 4);
  }
}

// ------------------------------------------------------------------
extern "C" void kernel_launch(void* const* d_in, const int* in_sizes, int n_in,
                              void* d_out, int out_size, void* d_ws, size_t ws_size,
                              hipStream_t stream) {
  (void)in_sizes; (void)n_in; (void)out_size;
  const float* x = (const float*)d_in[0];
  const float* A = (const float*)d_in[1];
  float* out = (float*)d_out;
  float* M = (float*)d_ws;

  const size_t need = (size_t)B_ * NP_ * MSTRIDE * sizeof(float);  // ~38 MB
  if (ws_size < need) return;

  k1_build<<<dim3(33, B_), 256, 0, stream>>>(x, A, M);
  k2_expm<<<dim3((B_ * NP_ * 4) / 256), 256, 0, stream>>>(M);  // 1030 blocks
  k3_chain<<<dim3(T_ / 64, B_), 256, 0, stream>>>(M, x, out);
}